// Round 7
// baseline (262.742 us; speedup 1.0000x reference)
//
#include <hip/hip_runtime.h>
#include <hip/hip_bf16.h>
#include <stdint.h>

#define NB 4
#define NQL 1024
#define NL 2048
#define NH 16
#define NKVH 4
#define ND 128
#define KVBLK 32
#define NROWS (NB * NH * NQL)
// (1/sqrt(128)) * log2(e): scores land in log2 domain, softmax uses exp2
#define QSCALE_LOG2E 0.1275174340213733f

typedef __bf16 bf16_t;
typedef __bf16 bf16x4 __attribute__((ext_vector_type(4)));
typedef __bf16 bf16x8 __attribute__((ext_vector_type(8)));
typedef float f32x4 __attribute__((ext_vector_type(4)));
typedef float f32x16 __attribute__((ext_vector_type(16)));
typedef uint32_t u32;
typedef unsigned short u16;

__device__ __forceinline__ void gload_lds16(const void* g, void* l) {
  __builtin_amdgcn_global_load_lds((const __attribute__((address_space(1))) void*)g,
                                   (__attribute__((address_space(3))) void*)l,
                                   16, 0, 0);
}

__device__ __forceinline__ u32 pack_bf16(float a, float b) {
  u32 ua = (u32)__builtin_bit_cast(u16, (bf16_t)a);
  u32 ub = (u32)__builtin_bit_cast(u16, (bf16_t)b);
  return ua | (ub << 16);
}

// ---------------------------------------------------------------------------
// Kernel 1: scatter new k/v into caches -> f32 outputs; also bf16 K copy to ws.
// ---------------------------------------------------------------------------
__global__ __launch_bounds__(256) void update_cache_kernel(
    const float* __restrict__ knew,
    const float* __restrict__ vnew,
    const float* __restrict__ cache_k,
    const float* __restrict__ cache_v,
    const int*   __restrict__ seq_lens,
    float* __restrict__ new_ck,
    float* __restrict__ new_cv,
    bf16_t* __restrict__ kb)
{
  const int n4 = NB * NKVH * NL * ND / 4;
  for (int i = blockIdx.x * blockDim.x + threadIdx.x; i < 2 * n4;
       i += gridDim.x * blockDim.x) {
    const int which = i >= n4;
    const int j   = which ? i - n4 : i;
    const int d4  = j & 31;
    const int l   = (j >> 5) & (NL - 1);
    const int kvh = (j >> 16) & (NKVH - 1);
    const int b   = j >> 18;
    const int s   = seq_lens[b];
    float4 val;
    if (l >= s && l < s + NQL) {
      const float* nsrc = which ? vnew : knew;
      val = *(const float4*)(nsrc + (((size_t)(b * NQL + (l - s))) * NKVH + kvh) * ND + d4 * 4);
    } else {
      const float* csrc = which ? cache_v : cache_k;
      val = *(const float4*)(csrc + (((size_t)(b * NKVH + kvh)) * NL + l) * ND + d4 * 4);
    }
    const size_t coff = (((size_t)(b * NKVH + kvh)) * NL + l) * ND + d4 * 4;
    float* dst = which ? new_cv : new_ck;
    *(float4*)(dst + coff) = val;
    if (!which) {
      bf16x4 kv;
      kv[0] = (bf16_t)val.x; kv[1] = (bf16_t)val.y;
      kv[2] = (bf16_t)val.z; kv[3] = (bf16_t)val.w;
      *(bf16x4*)(kb + coff) = kv;
    }
  }
}

// ---------------------------------------------------------------------------
// Kernel 2: build bf16 V^T [B][KVH][D][L] from updated f32 V cache.
// ---------------------------------------------------------------------------
__global__ __launch_bounds__(256) void transpose_v_kernel(
    const float* __restrict__ new_cv, bf16_t* __restrict__ vt)
{
  __shared__ float T[64][129];
  const int tid = threadIdx.x;
  const int bid = blockIdx.x;        // B*KVH*(NL/64) = 512
  const int lt  = bid & 31;
  const int kvh = (bid >> 5) & (NKVH - 1);
  const int b   = bid >> 7;
  const int l0  = lt * 64;

  const float* src = new_cv + (((size_t)(b * NKVH + kvh)) * NL + l0) * ND;
  #pragma unroll
  for (int j = 0; j < 8; ++j) {
    const int i   = tid + j * 256;
    const int row = i >> 5, c4 = i & 31;
    float4 v = *(const float4*)(src + row * ND + c4 * 4);
    T[row][c4 * 4 + 0] = v.x; T[row][c4 * 4 + 1] = v.y;
    T[row][c4 * 4 + 2] = v.z; T[row][c4 * 4 + 3] = v.w;
  }
  __syncthreads();
  bf16_t* dst = vt + ((size_t)(b * NKVH + kvh)) * ND * NL;
  #pragma unroll
  for (int j = 0; j < 4; ++j) {
    const int c = tid + j * 256;
    const int d = c >> 3, l8 = c & 7;
    bf16x8 o;
    #pragma unroll
    for (int e = 0; e < 8; ++e) o[e] = (bf16_t)T[l8 * 8 + e][d];
    *(bf16x8*)(dst + (size_t)d * NL + l0 + l8 * 8) = o;
  }
}

// ---------------------------------------------------------------------------
// Kernel 3: KV-split pipelined flash attention, 32x32 swapped MFMA.
// Block = 4 waves x 32 q-rows = 128-q tile; KVBLK=32; LDS 32 KB ->
// 4 blocks/CU with launch_bounds(256,4). nspl blocks cover disjoint KV
// halves of each tile; partial (O,m,l) merged by combine_kernel.
// Schedule (verified R5): phase t: barrier; STAGE_K(cur, t+2);
// STAGE_V(cur^1, t+1); QKT(t+1 from Kl[cur^1]); SOFTPV(t from Vl[cur]).
// ---------------------------------------------------------------------------
// K tile: 32 rows x 256B (16 chunks), chunk ^= (row&7).
#define STAGE_K(buf, tt) do {                                                \
    const int l0s = (tt) * KVBLK;                                            \
    _Pragma("unroll")                                                        \
    for (int j = 0; j < 2; ++j) {                                            \
      const int ck = tid + j * 256;                                          \
      const int kr = ck >> 4, kc2 = (ck & 15) ^ (kr & 7);                    \
      gload_lds16(kbb + (size_t)(l0s + kr) * ND + kc2 * 8,                   \
                  &Kl[buf][(wave * 64 + j * 256) * 8]);                      \
    }                                                                        \
  } while (0)

// V^T tile: 128 rows x 64B (4 chunks), chunk ^= (row ^ (row>>2)) & 3.
#define STAGE_V(buf, tt) do {                                                \
    const int l0s = (tt) * KVBLK;                                            \
    _Pragma("unroll")                                                        \
    for (int j = 0; j < 2; ++j) {                                            \
      const int ck = tid + j * 256;                                          \
      const int vr = ck >> 2, vc2 = (ck & 3) ^ ((vr ^ (vr >> 2)) & 3);       \
      gload_lds16(vtb + (size_t)vr * NL + (l0s + vc2 * 8),                   \
                  &Vl[buf][(wave * 64 + j * 256) * 8]);                      \
    }                                                                        \
  } while (0)

// S^T(tile) = K.Q from Kl[KBI] into SB (f32x16); rows l = l5, cols q.
#define QKT(SB, KBI) do {                                                    \
    f32x16 acc = (f32x16)(0.f);                                              \
    _Pragma("unroll")                                                        \
    for (int kc = 0; kc < 8; ++kc) {                                         \
      bf16x8 kf = *(const bf16x8*)                                           \
          &Kl[KBI][(l5 * 16 + ((kc * 2 + hi5) ^ (l5 & 7))) * 8];             \
      acc = __builtin_amdgcn_mfma_f32_32x32x16_bf16(kf, qf[kc], acc, 0, 0, 0); \
    }                                                                        \
    SB = acc;                                                                \
  } while (0)

// mask + online softmax + PV for tile at L0 using SB and Vl[VBI].
// Lane holds S^T[l = (rr&3) + 8*(rr>>2) + 4*hi5][q = l5].
#define SOFTPV(SB, VBI, L0) do {                                             \
    if ((L0) + 31 > s + qw) {                                                \
      const int lim = s + q - (L0);                                          \
      _Pragma("unroll")                                                      \
      for (int rr = 0; rr < 16; ++rr) {                                      \
        const int ll = (rr & 3) + 8 * (rr >> 2) + 4 * hi5;                   \
        if (ll > lim) SB[rr] = -1e30f;                                       \
      }                                                                      \
    }                                                                        \
    float pm = SB[0];                                                        \
    _Pragma("unroll")                                                        \
    for (int rr = 1; rr < 16; ++rr) pm = fmaxf(pm, SB[rr]);                  \
    pm = fmaxf(pm, __shfl_xor(pm, 32, 64));                                  \
    if (!__all(pm - mreg <= 8.f)) {                                          \
      const float mnew  = fmaxf(mreg, pm);                                   \
      const float alpha = exp2f(mreg - mnew);                                \
      mreg = mnew;                                                           \
      lreg *= alpha;                                                         \
      _Pragma("unroll")                                                      \
      for (int i = 0; i < 4; ++i) oacc[i] *= alpha;                          \
    }                                                                        \
    float ts = 0.f;                                                          \
    _Pragma("unroll")                                                        \
    for (int rr = 0; rr < 16; ++rr) {                                        \
      const float p = exp2f(SB[rr] - mreg);                                  \
      SB[rr] = p;                                                            \
      ts += p;                                                               \
    }                                                                        \
    lreg += ts + __shfl_xor(ts, 32, 64);                                     \
    u32 pk[4][2];                                                            \
    _Pragma("unroll")                                                        \
    for (int m = 0; m < 4; ++m) {                                            \
      pk[m][0] = pack_bf16(SB[m * 4 + 0], SB[m * 4 + 1]);                    \
      pk[m][1] = pack_bf16(SB[m * 4 + 2], SB[m * 4 + 3]);                    \
    }                                                                        \
    bf16x8 pb[2];                                                            \
    _Pragma("unroll")                                                        \
    for (int c = 0; c < 2; ++c) {                                            \
      const u32 own0 = hi5 ? pk[c * 2 + 1][0] : pk[c * 2][0];                \
      const u32 own1 = hi5 ? pk[c * 2 + 1][1] : pk[c * 2][1];                \
      const u32 snd0 = hi5 ? pk[c * 2][0] : pk[c * 2 + 1][0];                \
      const u32 snd1 = hi5 ? pk[c * 2][1] : pk[c * 2 + 1][1];                \
      const u32 r0 = (u32)__shfl_xor((int)snd0, 32, 64);                     \
      const u32 r1 = (u32)__shfl_xor((int)snd1, 32, 64);                     \
      union { u32 w[4]; bf16x8 v; } uu;                                      \
      uu.w[0] = hi5 ? r0 : own0;                                             \
      uu.w[1] = hi5 ? r1 : own1;                                             \
      uu.w[2] = hi5 ? own0 : r0;                                             \
      uu.w[3] = hi5 ? own1 : r1;                                             \
      pb[c] = uu.v;                                                          \
    }                                                                        \
    _Pragma("unroll")                                                        \
    for (int ds = 0; ds < 4; ++ds) {                                         \
      const int vrow = ds * 32 + l5;                                         \
      _Pragma("unroll")                                                      \
      for (int c = 0; c < 2; ++c) {                                          \
        bf16x8 va = *(const bf16x8*)                                         \
            &Vl[VBI][(vrow * 4 + ((c * 2 + hi5) ^ ((l5 ^ (l5 >> 2)) & 3))) * 8]; \
        oacc[ds] = __builtin_amdgcn_mfma_f32_32x32x16_bf16(va, pb[c], oacc[ds], 0, 0, 0); \
      }                                                                      \
    }                                                                        \
  } while (0)

__global__ __launch_bounds__(256, 4) void attn_kernel(
    const float* __restrict__ qin, const bf16_t* __restrict__ kb,
    const bf16_t* __restrict__ vt, const int* __restrict__ seq_lens,
    float* __restrict__ out, bf16_t* __restrict__ opart,
    float2* __restrict__ ml, int nspl)
{
  __shared__ bf16_t Kl[2][KVBLK * ND];   // 8 KB x2
  __shared__ bf16_t Vl[2][ND * KVBLK];   // 8 KB x2

  const int tid  = threadIdx.x;
  const int wave = tid >> 6, lane = tid & 63;
  const int l5   = lane & 31;            // q column / l-row index
  const int hi5  = lane >> 5;

  // bid = ((b*NKVH + kvh)*nspl + sp)*32 + hh*8 + qt : 32 consecutive blocks
  // share one (b,kvh,KV-half) panel for L2 locality.
  const int bid = blockIdx.x;
  const int qt  = bid & 7;
  const int hh  = (bid >> 3) & 3;
  const int g   = bid >> 5;              // (b*NKVH + kvh)*nspl + sp
  const int sp  = g - (g / nspl) * nspl;
  const int bk  = g / nspl;              // b*NKVH + kvh
  const int kvh = bk & (NKVH - 1);
  const int b   = bk >> 2;
  const int h   = kvh * 4 + hh;
  const int s   = seq_lens[b];
  const int qw  = qt * 128 + wave * 32;
  const int q   = qw + l5;

  const bf16_t* kbb = kb + ((size_t)bk) * NL * ND;
  const bf16_t* vtb = vt + ((size_t)bk) * ND * NL;

  // Q fragments (B operand): qf[kc][j] = Q[q][kc*16 + hi5*8 + j]
  bf16x8 qf[8];
  {
    const float* qb = qin + ((size_t)((b * NQL + q) * NH + h)) * ND;
    #pragma unroll
    for (int kc = 0; kc < 8; ++kc) {
      float4 x0 = *(const float4*)(qb + kc * 16 + hi5 * 8);
      float4 x1 = *(const float4*)(qb + kc * 16 + hi5 * 8 + 4);
      bf16x8 f;
      f[0] = (bf16_t)(x0.x * QSCALE_LOG2E); f[1] = (bf16_t)(x0.y * QSCALE_LOG2E);
      f[2] = (bf16_t)(x0.z * QSCALE_LOG2E); f[3] = (bf16_t)(x0.w * QSCALE_LOG2E);
      f[4] = (bf16_t)(x1.x * QSCALE_LOG2E); f[5] = (bf16_t)(x1.y * QSCALE_LOG2E);
      f[6] = (bf16_t)(x1.z * QSCALE_LOG2E); f[7] = (bf16_t)(x1.w * QSCALE_LOG2E);
      qf[kc] = f;
    }
  }

  f32x16 oacc[4];   // O^T[d = ds*32 + 8*rq + 4*hi5 + rr][q = l5]
  #pragma unroll
  for (int i = 0; i < 4; ++i) oacc[i] = (f32x16)(0.f);
  float mreg = -1e30f, lreg = 0.f;

  // block-level tile range for this KV split part
  const int nt   = (s + qt * 128 + 128 + KVBLK - 1) / KVBLK;   // >= 4
  const int half = (nt + nspl - 1) / nspl;
  const int t0   = sp * half;
  const int t1   = (sp + 1 == nspl) ? nt : (t0 + half);
  const int vlim = s + qw + 31;          // wave's last valid l

  // ---- prologue: stage K(t0), V(t0), K(t0+1); compute QK(t0) ----
  STAGE_K(0, t0);
  STAGE_V(0, t0);
  STAGE_K(1, t0 + 1);
  __syncthreads();

  f32x16 sA, sB;
  QKT(sA, 0);

  // ---- main loop, 2 phases per trip, all buffer indices static ----
  for (int t = t0; ; t += 2) {
    // --- phase even: tile t uses Kl[0]/Vl[0] ---
    __syncthreads();                     // drains K(t+1)->Kl[1], V(t)->Vl[0]
    if (t + 2 < t1) STAGE_K(0, t + 2);
    if (t + 1 < t1) STAGE_V(1, t + 1);
    const bool gB = (t + 1 < t1) && ((t + 1) * KVBLK <= vlim);
    if (gB) QKT(sB, 1);
    if (t * KVBLK <= vlim) SOFTPV(sA, 0, t * KVBLK);
    if (t + 1 >= t1) break;

    // --- phase odd: tile t+1 uses Kl[1]/Vl[1] ---
    __syncthreads();                     // drains K(t+2)->Kl[0], V(t+1)->Vl[1]
    if (t + 3 < t1) STAGE_K(1, t + 3);
    if (t + 2 < t1) STAGE_V(0, t + 2);
    const bool gA = (t + 2 < t1) && ((t + 2) * KVBLK <= vlim);
    if (gA) QKT(sA, 0);
    if ((t + 1) * KVBLK <= vlim) SOFTPV(sB, 1, (t + 1) * KVBLK);
    if (t + 2 >= t1) break;
  }

  const int row = (b * NH + h) * NQL + q;
  if (nspl == 1) {
    // direct write (fallback): normalize, d = ds*32 + rq*8 + hi5*4 + rr
    const float linv = 1.0f / lreg;
    float* ob = out + ((size_t)((b * NQL + q) * NH + h)) * ND;
    #pragma unroll
    for (int ds = 0; ds < 4; ++ds)
      #pragma unroll
      for (int rq = 0; rq < 4; ++rq) {
        float4 v;
        v.x = oacc[ds][rq * 4 + 0] * linv;
        v.y = oacc[ds][rq * 4 + 1] * linv;
        v.z = oacc[ds][rq * 4 + 2] * linv;
        v.w = oacc[ds][rq * 4 + 3] * linv;
        *(float4*)(ob + ds * 32 + rq * 8 + hi5 * 4) = v;
      }
  } else {
    // partial write: unnormalized bf16 O + (m,l)
    bf16_t* ob = opart + ((size_t)sp * NROWS + row) * ND;
    #pragma unroll
    for (int ds = 0; ds < 4; ++ds)
      #pragma unroll
      for (int rq = 0; rq < 4; ++rq) {
        bf16x4 v;
        v[0] = (bf16_t)oacc[ds][rq * 4 + 0];
        v[1] = (bf16_t)oacc[ds][rq * 4 + 1];
        v[2] = (bf16_t)oacc[ds][rq * 4 + 2];
        v[3] = (bf16_t)oacc[ds][rq * 4 + 3];
        *(bf16x4*)(ob + ds * 32 + rq * 8 + hi5 * 4) = v;
      }
    if (hi5 == 0) ml[(size_t)sp * NROWS + row] = make_float2(mreg, lreg);
  }
}

// ---------------------------------------------------------------------------
// Kernel 4: merge the 2 KV-split partials. gid = row*32 + d4.
// ---------------------------------------------------------------------------
__global__ __launch_bounds__(256) void combine_kernel(
    const bf16_t* __restrict__ opart, const float2* __restrict__ ml,
    float* __restrict__ out)
{
  const int gid = blockIdx.x * 256 + threadIdx.x;   // NROWS*32 threads
  const int row = gid >> 5, d4 = gid & 31;
  const float2 ml0 = ml[row];
  const float2 ml1 = ml[NROWS + row];
  const float M  = fmaxf(ml0.x, ml1.x);
  const float a0 = exp2f(ml0.x - M), a1 = exp2f(ml1.x - M);
  const float linv = 1.0f / (a0 * ml0.y + a1 * ml1.y);
  bf16x4 o0 = *(const bf16x4*)(opart + (size_t)row * ND + d4 * 4);
  bf16x4 o1 = *(const bf16x4*)(opart + ((size_t)NROWS + row) * ND + d4 * 4);
  const int q = row & (NQL - 1), h = (row >> 10) & (NH - 1), b = row >> 14;
  float4 v;
  v.x = (a0 * (float)o0[0] + a1 * (float)o1[0]) * linv;
  v.y = (a0 * (float)o0[1] + a1 * (float)o1[1]) * linv;
  v.z = (a0 * (float)o0[2] + a1 * (float)o1[2]) * linv;
  v.w = (a0 * (float)o0[3] + a1 * (float)o1[3]) * linv;
  *(float4*)(out + ((size_t)((b * NQL + q) * NH + h)) * ND + d4 * 4) = v;
}

// ---------------------------------------------------------------------------
extern "C" void kernel_launch(void* const* d_in, const int* in_sizes, int n_in,
                              void* d_out, int out_size, void* d_ws, size_t ws_size,
                              hipStream_t stream)
{
  const float* q        = (const float*)d_in[0];
  const float* k        = (const float*)d_in[1];
  const float* v        = (const float*)d_in[2];
  const float* cache_k  = (const float*)d_in[3];
  const float* cache_v  = (const float*)d_in[4];
  const int*   seq_lens = (const int*)d_in[5];

  float* out    = (float*)d_out;
  float* new_ck = out + (size_t)NB * NQL * NH * ND;
  float* new_cv = new_ck + (size_t)NB * NKVH * NL * ND;

  const size_t cache_elems = (size_t)NB * NKVH * NL * ND;   // 4 MiB elems
  bf16_t* kb    = (bf16_t*)d_ws;                            // 8 MB
  bf16_t* vt    = kb + cache_elems;                         // 8 MB
  bf16_t* opart = vt + cache_elems;                         // 32 MB (2 parts)
  float2* ml    = (float2*)(opart + (size_t)2 * NROWS * ND);// 1 MB

  const size_t need = (size_t)((char*)(ml + 2 * NROWS) - (char*)d_ws);
  const int nspl = (ws_size >= need) ? 2 : 1;

  hipLaunchKernelGGL(update_cache_kernel, dim3(2048), dim3(256), 0, stream,
                     k, v, cache_k, cache_v, seq_lens, new_ck, new_cv, kb);
  hipLaunchKernelGGL(transpose_v_kernel, dim3(NB * NKVH * (NL / 64)), dim3(256), 0, stream,
                     new_cv, vt);
  hipLaunchKernelGGL(attn_kernel, dim3(NB * NKVH * nspl * 32), dim3(256), 0, stream,
                     q, kb, vt, seq_lens, out, opart, ml, nspl);
  if (nspl == 2)
    hipLaunchKernelGGL(combine_kernel, dim3(NROWS * 32 / 256), dim3(256), 0, stream,
                       opart, ml, out);
}

// Round 8
// 151.987 us; speedup vs baseline: 1.7287x; 1.7287x over previous
//
#include <hip/hip_runtime.h>
#include <hip/hip_bf16.h>
#include <stdint.h>

#define NB 4
#define NQL 1024
#define NL 2048
#define NH 16
#define NKVH 4
#define ND 128
#define KVBLK 32
#define NROWS (NB * NH * NQL)
// (1/sqrt(128)) * log2(e): scores land in log2 domain, softmax uses exp2
#define QSCALE_LOG2E 0.1275174340213733f

typedef __bf16 bf16_t;
typedef __bf16 bf16x4 __attribute__((ext_vector_type(4)));
typedef __bf16 bf16x8 __attribute__((ext_vector_type(8)));
typedef float f32x4 __attribute__((ext_vector_type(4)));
typedef float f32x16 __attribute__((ext_vector_type(16)));
typedef uint32_t u32;
typedef unsigned short u16;

__device__ __forceinline__ void gload_lds16(const void* g, void* l) {
  __builtin_amdgcn_global_load_lds((const __attribute__((address_space(1))) void*)g,
                                   (__attribute__((address_space(3))) void*)l,
                                   16, 0, 0);
}

__device__ __forceinline__ u32 pack_bf16(float a, float b) {
  u32 ua = (u32)__builtin_bit_cast(u16, (bf16_t)a);
  u32 ub = (u32)__builtin_bit_cast(u16, (bf16_t)b);
  return ua | (ub << 16);
}

// ---------------------------------------------------------------------------
// Kernel 1: scatter new k/v into caches -> f32 outputs; also bf16 K copy to ws.
// ---------------------------------------------------------------------------
__global__ __launch_bounds__(256) void update_cache_kernel(
    const float* __restrict__ knew,
    const float* __restrict__ vnew,
    const float* __restrict__ cache_k,
    const float* __restrict__ cache_v,
    const int*   __restrict__ seq_lens,
    float* __restrict__ new_ck,
    float* __restrict__ new_cv,
    bf16_t* __restrict__ kb)
{
  const int n4 = NB * NKVH * NL * ND / 4;
  for (int i = blockIdx.x * blockDim.x + threadIdx.x; i < 2 * n4;
       i += gridDim.x * blockDim.x) {
    const int which = i >= n4;
    const int j   = which ? i - n4 : i;
    const int d4  = j & 31;
    const int l   = (j >> 5) & (NL - 1);
    const int kvh = (j >> 16) & (NKVH - 1);
    const int b   = j >> 18;
    const int s   = seq_lens[b];
    float4 val;
    if (l >= s && l < s + NQL) {
      const float* nsrc = which ? vnew : knew;
      val = *(const float4*)(nsrc + (((size_t)(b * NQL + (l - s))) * NKVH + kvh) * ND + d4 * 4);
    } else {
      const float* csrc = which ? cache_v : cache_k;
      val = *(const float4*)(csrc + (((size_t)(b * NKVH + kvh)) * NL + l) * ND + d4 * 4);
    }
    const size_t coff = (((size_t)(b * NKVH + kvh)) * NL + l) * ND + d4 * 4;
    float* dst = which ? new_cv : new_ck;
    *(float4*)(dst + coff) = val;
    if (!which) {
      bf16x4 kv;
      kv[0] = (bf16_t)val.x; kv[1] = (bf16_t)val.y;
      kv[2] = (bf16_t)val.z; kv[3] = (bf16_t)val.w;
      *(bf16x4*)(kb + coff) = kv;
    }
  }
}

// ---------------------------------------------------------------------------
// Kernel 2: build bf16 V^T [B][KVH][D][L] from updated f32 V cache.
// ---------------------------------------------------------------------------
__global__ __launch_bounds__(256) void transpose_v_kernel(
    const float* __restrict__ new_cv, bf16_t* __restrict__ vt)
{
  __shared__ float T[64][129];
  const int tid = threadIdx.x;
  const int bid = blockIdx.x;        // B*KVH*(NL/64) = 512
  const int lt  = bid & 31;
  const int kvh = (bid >> 5) & (NKVH - 1);
  const int b   = bid >> 7;
  const int l0  = lt * 64;

  const float* src = new_cv + (((size_t)(b * NKVH + kvh)) * NL + l0) * ND;
  #pragma unroll
  for (int j = 0; j < 8; ++j) {
    const int i   = tid + j * 256;
    const int row = i >> 5, c4 = i & 31;
    float4 v = *(const float4*)(src + row * ND + c4 * 4);
    T[row][c4 * 4 + 0] = v.x; T[row][c4 * 4 + 1] = v.y;
    T[row][c4 * 4 + 2] = v.z; T[row][c4 * 4 + 3] = v.w;
  }
  __syncthreads();
  bf16_t* dst = vt + ((size_t)(b * NKVH + kvh)) * ND * NL;
  #pragma unroll
  for (int j = 0; j < 4; ++j) {
    const int c = tid + j * 256;
    const int d = c >> 3, l8 = c & 7;
    bf16x8 o;
    #pragma unroll
    for (int e = 0; e < 8; ++e) o[e] = (bf16_t)T[l8 * 8 + e][d];
    *(bf16x8*)(dst + (size_t)d * NL + l0 + l8 * 8) = o;
  }
}

// ---------------------------------------------------------------------------
// Kernel 3: KV-split pipelined flash attention, 32x32 swapped MFMA.
// Block = 4 waves x 32 q-rows; KVBLK=32; LDS 32 KB; launch_bounds(256,3)
// (VGPR cap 168 -- the R7 (256,4)=128 cap spilled oacc to scratch, 2.4x).
// Schedule (verified R5): phase t: barrier; STAGE_K(cur, t+2);
// STAGE_V(cur^1, t+1); QKT(t+1 from Kl[cur^1]); SOFTPV(t from Vl[cur]).
// ---------------------------------------------------------------------------
// K tile: 32 rows x 256B (16 chunks), chunk ^= (row&7).
#define STAGE_K(buf, tt) do {                                                \
    const int l0s = (tt) * KVBLK;                                            \
    _Pragma("unroll")                                                        \
    for (int j = 0; j < 2; ++j) {                                            \
      const int ck = tid + j * 256;                                          \
      const int kr = ck >> 4, kc2 = (ck & 15) ^ (kr & 7);                    \
      gload_lds16(kbb + (size_t)(l0s + kr) * ND + kc2 * 8,                   \
                  &Kl[buf][(wave * 64 + j * 256) * 8]);                      \
    }                                                                        \
  } while (0)

// V^T tile: 128 rows x 64B (4 chunks), chunk ^= (row ^ (row>>2)) & 3.
#define STAGE_V(buf, tt) do {                                                \
    const int l0s = (tt) * KVBLK;                                            \
    _Pragma("unroll")                                                        \
    for (int j = 0; j < 2; ++j) {                                            \
      const int ck = tid + j * 256;                                          \
      const int vr = ck >> 2, vc2 = (ck & 3) ^ ((vr ^ (vr >> 2)) & 3);       \
      gload_lds16(vtb + (size_t)vr * NL + (l0s + vc2 * 8),                   \
                  &Vl[buf][(wave * 64 + j * 256) * 8]);                      \
    }                                                                        \
  } while (0)

// S^T(tile) = K.Q from Kl[KBI] into SB (f32x16); rows l = l5, cols q.
#define QKT(SB, KBI) do {                                                    \
    f32x16 acc = (f32x16)(0.f);                                              \
    _Pragma("unroll")                                                        \
    for (int kc = 0; kc < 8; ++kc) {                                         \
      bf16x8 kf = *(const bf16x8*)                                           \
          &Kl[KBI][(l5 * 16 + ((kc * 2 + hi5) ^ (l5 & 7))) * 8];             \
      acc = __builtin_amdgcn_mfma_f32_32x32x16_bf16(kf, qf[kc], acc, 0, 0, 0); \
    }                                                                        \
    SB = acc;                                                                \
  } while (0)

// mask + online softmax + PV for tile at L0 using SB and Vl[VBI].
// Lane holds S^T[l = (rr&3) + 8*(rr>>2) + 4*hi5][q = l5].
#define SOFTPV(SB, VBI, L0) do {                                             \
    if ((L0) + 31 > s + qw) {                                                \
      const int lim = s + q - (L0);                                          \
      _Pragma("unroll")                                                      \
      for (int rr = 0; rr < 16; ++rr) {                                      \
        const int ll = (rr & 3) + 8 * (rr >> 2) + 4 * hi5;                   \
        if (ll > lim) SB[rr] = -1e30f;                                       \
      }                                                                      \
    }                                                                        \
    float pm = SB[0];                                                        \
    _Pragma("unroll")                                                        \
    for (int rr = 1; rr < 16; ++rr) pm = fmaxf(pm, SB[rr]);                  \
    pm = fmaxf(pm, __shfl_xor(pm, 32, 64));                                  \
    if (!__all(pm - mreg <= 8.f)) {                                          \
      const float mnew  = fmaxf(mreg, pm);                                   \
      const float alpha = exp2f(mreg - mnew);                                \
      mreg = mnew;                                                           \
      lreg *= alpha;                                                         \
      _Pragma("unroll")                                                      \
      for (int i = 0; i < 4; ++i) oacc[i] *= alpha;                          \
    }                                                                        \
    float ts = 0.f;                                                          \
    _Pragma("unroll")                                                        \
    for (int rr = 0; rr < 16; ++rr) {                                        \
      const float p = exp2f(SB[rr] - mreg);                                  \
      SB[rr] = p;                                                            \
      ts += p;                                                               \
    }                                                                        \
    lreg += ts + __shfl_xor(ts, 32, 64);                                     \
    u32 pk[4][2];                                                            \
    _Pragma("unroll")                                                        \
    for (int m = 0; m < 4; ++m) {                                            \
      pk[m][0] = pack_bf16(SB[m * 4 + 0], SB[m * 4 + 1]);                    \
      pk[m][1] = pack_bf16(SB[m * 4 + 2], SB[m * 4 + 3]);                    \
    }                                                                        \
    bf16x8 pb[2];                                                            \
    _Pragma("unroll")                                                        \
    for (int c = 0; c < 2; ++c) {                                            \
      const u32 own0 = hi5 ? pk[c * 2 + 1][0] : pk[c * 2][0];                \
      const u32 own1 = hi5 ? pk[c * 2 + 1][1] : pk[c * 2][1];                \
      const u32 snd0 = hi5 ? pk[c * 2][0] : pk[c * 2 + 1][0];                \
      const u32 snd1 = hi5 ? pk[c * 2][1] : pk[c * 2 + 1][1];                \
      const u32 r0 = (u32)__shfl_xor((int)snd0, 32, 64);                     \
      const u32 r1 = (u32)__shfl_xor((int)snd1, 32, 64);                     \
      union { u32 w[4]; bf16x8 v; } uu;                                      \
      uu.w[0] = hi5 ? r0 : own0;                                             \
      uu.w[1] = hi5 ? r1 : own1;                                             \
      uu.w[2] = hi5 ? own0 : r0;                                             \
      uu.w[3] = hi5 ? own1 : r1;                                             \
      pb[c] = uu.v;                                                          \
    }                                                                        \
    _Pragma("unroll")                                                        \
    for (int ds = 0; ds < 4; ++ds) {                                         \
      const int vrow = ds * 32 + l5;                                         \
      _Pragma("unroll")                                                      \
      for (int c = 0; c < 2; ++c) {                                          \
        bf16x8 va = *(const bf16x8*)                                         \
            &Vl[VBI][(vrow * 4 + ((c * 2 + hi5) ^ ((l5 ^ (l5 >> 2)) & 3))) * 8]; \
        oacc[ds] = __builtin_amdgcn_mfma_f32_32x32x16_bf16(va, pb[c], oacc[ds], 0, 0, 0); \
      }                                                                      \
    }                                                                        \
  } while (0)

__global__ __launch_bounds__(256, 3) void attn_kernel(
    const float* __restrict__ qin, const bf16_t* __restrict__ kb,
    const bf16_t* __restrict__ vt, const int* __restrict__ seq_lens,
    float* __restrict__ out, bf16_t* __restrict__ opart,
    float2* __restrict__ ml, int nspl)
{
  __shared__ bf16_t Kl[2][KVBLK * ND];   // 8 KB x2
  __shared__ bf16_t Vl[2][ND * KVBLK];   // 8 KB x2

  const int tid  = threadIdx.x;
  const int wave = tid >> 6, lane = tid & 63;
  const int l5   = lane & 31;            // q column / l-row index
  const int hi5  = lane >> 5;

  // Work-aware mapping: bid = chunk*256 + bk*16 + hh*4 + pp.
  // Co-scheduled blocks {x, x+256, x+512, x+768} share (b,kvh,hh) -> same
  // K/V panel (L2 reuse) and get (qt,sp) with sum(qt)=14 -> per-CU balance.
  static const __device__ int8_t QT_TAB[16] = {0,1,2,3, 7,6,5,4, 3,2,1,0, 4,5,6,7};
  const int bid   = blockIdx.x;
  const int chunk = bid >> 8;
  const int r     = bid & 255;
  const int bk    = r >> 4;              // b*NKVH + kvh
  const int hh    = (r >> 2) & 3;
  const int pp    = r & 3;
  const int idx   = chunk * 4 + pp;
  const int qt    = QT_TAB[idx];
  const int spq   = idx >> 3;            // sp when nspl==2 (second occurrence)
  const int sp    = (nspl == 2) ? spq : 0;
  const int kvh   = bk & (NKVH - 1);
  const int b     = bk >> 2;
  const int h     = kvh * 4 + hh;
  const int s     = seq_lens[b];
  const int qw    = qt * 128 + wave * 32;
  const int q     = qw + l5;

  const bf16_t* kbb = kb + ((size_t)bk) * NL * ND;
  const bf16_t* vtb = vt + ((size_t)bk) * ND * NL;

  // Q fragments (B operand): qf[kc][j] = Q[q][kc*16 + hi5*8 + j]
  bf16x8 qf[8];
  {
    const float* qb = qin + ((size_t)((b * NQL + q) * NH + h)) * ND;
    #pragma unroll
    for (int kc = 0; kc < 8; ++kc) {
      float4 x0 = *(const float4*)(qb + kc * 16 + hi5 * 8);
      float4 x1 = *(const float4*)(qb + kc * 16 + hi5 * 8 + 4);
      bf16x8 f;
      f[0] = (bf16_t)(x0.x * QSCALE_LOG2E); f[1] = (bf16_t)(x0.y * QSCALE_LOG2E);
      f[2] = (bf16_t)(x0.z * QSCALE_LOG2E); f[3] = (bf16_t)(x0.w * QSCALE_LOG2E);
      f[4] = (bf16_t)(x1.x * QSCALE_LOG2E); f[5] = (bf16_t)(x1.y * QSCALE_LOG2E);
      f[6] = (bf16_t)(x1.z * QSCALE_LOG2E); f[7] = (bf16_t)(x1.w * QSCALE_LOG2E);
      qf[kc] = f;
    }
  }

  f32x16 oacc[4];   // O^T[d = ds*32 + 8*rq + 4*hi5 + rr][q = l5]
  #pragma unroll
  for (int i = 0; i < 4; ++i) oacc[i] = (f32x16)(0.f);
  float mreg = -1e30f, lreg = 0.f;

  // block-level tile range for this KV split part (each part >= 2 tiles)
  const int nt   = (s + qt * 128 + 128 + KVBLK - 1) / KVBLK;   // >= 4
  const int half = (nspl == 2) ? ((nt + 1) >> 1) : nt;
  const int t0   = sp * half;
  const int t1   = (sp + 1 == nspl) ? nt : (t0 + half);
  const int vlim = s + qw + 31;          // wave's last valid l

  // ---- prologue: stage K(t0), V(t0), K(t0+1); compute QK(t0) ----
  STAGE_K(0, t0);
  STAGE_V(0, t0);
  STAGE_K(1, t0 + 1);
  __syncthreads();

  f32x16 sA, sB;
  QKT(sA, 0);

  // ---- main loop, 2 phases per trip, all buffer indices static ----
  for (int t = t0; ; t += 2) {
    // --- phase even: tile t uses Kl[0]/Vl[0] ---
    __syncthreads();                     // drains K(t+1)->Kl[1], V(t)->Vl[0]
    if (t + 2 < t1) STAGE_K(0, t + 2);
    if (t + 1 < t1) STAGE_V(1, t + 1);
    const bool gB = (t + 1 < t1) && ((t + 1) * KVBLK <= vlim);
    if (gB) QKT(sB, 1);
    if (t * KVBLK <= vlim) SOFTPV(sA, 0, t * KVBLK);
    if (t + 1 >= t1) break;

    // --- phase odd: tile t+1 uses Kl[1]/Vl[1] ---
    __syncthreads();                     // drains K(t+2)->Kl[0], V(t+1)->Vl[1]
    if (t + 3 < t1) STAGE_K(1, t + 3);
    if (t + 2 < t1) STAGE_V(0, t + 2);
    const bool gA = (t + 2 < t1) && ((t + 2) * KVBLK <= vlim);
    if (gA) QKT(sA, 0);
    if ((t + 1) * KVBLK <= vlim) SOFTPV(sB, 1, (t + 1) * KVBLK);
    if (t + 2 >= t1) break;
  }

  const int row = (b * NH + h) * NQL + q;
  if (nspl == 1) {
    // direct write (fallback): normalize, d = ds*32 + rq*8 + hi5*4 + rr
    const float linv = 1.0f / lreg;
    float* ob = out + ((size_t)((b * NQL + q) * NH + h)) * ND;
    #pragma unroll
    for (int ds = 0; ds < 4; ++ds)
      #pragma unroll
      for (int rq = 0; rq < 4; ++rq) {
        float4 v;
        v.x = oacc[ds][rq * 4 + 0] * linv;
        v.y = oacc[ds][rq * 4 + 1] * linv;
        v.z = oacc[ds][rq * 4 + 2] * linv;
        v.w = oacc[ds][rq * 4 + 3] * linv;
        *(float4*)(ob + ds * 32 + rq * 8 + hi5 * 4) = v;
      }
  } else {
    // partial write: unnormalized bf16 O + (m,l)
    bf16_t* ob = opart + ((size_t)sp * NROWS + row) * ND;
    #pragma unroll
    for (int ds = 0; ds < 4; ++ds)
      #pragma unroll
      for (int rq = 0; rq < 4; ++rq) {
        bf16x4 v;
        v[0] = (bf16_t)oacc[ds][rq * 4 + 0];
        v[1] = (bf16_t)oacc[ds][rq * 4 + 1];
        v[2] = (bf16_t)oacc[ds][rq * 4 + 2];
        v[3] = (bf16_t)oacc[ds][rq * 4 + 3];
        *(bf16x4*)(ob + ds * 32 + rq * 8 + hi5 * 4) = v;
      }
    if (hi5 == 0) ml[(size_t)sp * NROWS + row] = make_float2(mreg, lreg);
  }
}

// ---------------------------------------------------------------------------
// Kernel 4: merge the 2 KV-split partials. gid = row*32 + d4.
// ---------------------------------------------------------------------------
__global__ __launch_bounds__(256) void combine_kernel(
    const bf16_t* __restrict__ opart, const float2* __restrict__ ml,
    float* __restrict__ out)
{
  const int gid = blockIdx.x * 256 + threadIdx.x;   // NROWS*32 threads
  const int row = gid >> 5, d4 = gid & 31;
  const float2 ml0 = ml[row];
  const float2 ml1 = ml[NROWS + row];
  const float M  = fmaxf(ml0.x, ml1.x);
  const float a0 = exp2f(ml0.x - M), a1 = exp2f(ml1.x - M);
  const float linv = 1.0f / (a0 * ml0.y + a1 * ml1.y);
  bf16x4 o0 = *(const bf16x4*)(opart + (size_t)row * ND + d4 * 4);
  bf16x4 o1 = *(const bf16x4*)(opart + ((size_t)NROWS + row) * ND + d4 * 4);
  const int q = row & (NQL - 1), h = (row >> 10) & (NH - 1), b = row >> 14;
  float4 v;
  v.x = (a0 * (float)o0[0] + a1 * (float)o1[0]) * linv;
  v.y = (a0 * (float)o0[1] + a1 * (float)o1[1]) * linv;
  v.z = (a0 * (float)o0[2] + a1 * (float)o1[2]) * linv;
  v.w = (a0 * (float)o0[3] + a1 * (float)o1[3]) * linv;
  *(float4*)(out + ((size_t)((b * NQL + q) * NH + h)) * ND + d4 * 4) = v;
}

// ---------------------------------------------------------------------------
extern "C" void kernel_launch(void* const* d_in, const int* in_sizes, int n_in,
                              void* d_out, int out_size, void* d_ws, size_t ws_size,
                              hipStream_t stream)
{
  const float* q        = (const float*)d_in[0];
  const float* k        = (const float*)d_in[1];
  const float* v        = (const float*)d_in[2];
  const float* cache_k  = (const float*)d_in[3];
  const float* cache_v  = (const float*)d_in[4];
  const int*   seq_lens = (const int*)d_in[5];

  float* out    = (float*)d_out;
  float* new_ck = out + (size_t)NB * NQL * NH * ND;
  float* new_cv = new_ck + (size_t)NB * NKVH * NL * ND;

  const size_t cache_elems = (size_t)NB * NKVH * NL * ND;   // 4 Mi elems
  bf16_t* kb    = (bf16_t*)d_ws;                            // 8 MB
  bf16_t* vt    = kb + cache_elems;                         // 8 MB
  bf16_t* opart = vt + cache_elems;                         // 32 MB (2 parts)
  float2* ml    = (float2*)(opart + (size_t)2 * NROWS * ND);// 1 MB

  const size_t need = (size_t)((char*)(ml + 2 * NROWS) - (char*)d_ws);
  const int nspl = (ws_size >= need) ? 2 : 1;

  hipLaunchKernelGGL(update_cache_kernel, dim3(2048), dim3(256), 0, stream,
                     k, v, cache_k, cache_v, seq_lens, new_ck, new_cv, kb);
  hipLaunchKernelGGL(transpose_v_kernel, dim3(NB * NKVH * (NL / 64)), dim3(256), 0, stream,
                     new_cv, vt);
  hipLaunchKernelGGL(attn_kernel, dim3(nspl == 2 ? 1024 : 512), dim3(256), 0, stream,
                     q, kb, vt, seq_lens, out, opart, ml, nspl);
  if (nspl == 2)
    hipLaunchKernelGGL(combine_kernel, dim3(NROWS * 32 / 256), dim3(256), 0, stream,
                       opart, ml, out);
}

// Round 9
// 120.142 us; speedup vs baseline: 2.1869x; 1.2651x over previous
//
#include <hip/hip_runtime.h>
#include <hip/hip_bf16.h>
#include <stdint.h>

#define NB 4
#define NQL 1024
#define NL 2048
#define NH 16
#define NKVH 4
#define ND 128
#define KVBLK 32
#define NROWS (NB * NH * NQL)
// (1/sqrt(128)) * log2(e): scores land in log2 domain, softmax uses exp2
#define QSCALE_LOG2E 0.1275174340213733f

typedef __bf16 bf16_t;
typedef __bf16 bf16x4 __attribute__((ext_vector_type(4)));
typedef __bf16 bf16x8 __attribute__((ext_vector_type(8)));
typedef float f32x4 __attribute__((ext_vector_type(4)));
typedef float f32x16 __attribute__((ext_vector_type(16)));
typedef uint32_t u32;
typedef unsigned short u16;

__device__ __forceinline__ void gload_lds16(const void* g, void* l) {
  __builtin_amdgcn_global_load_lds((const __attribute__((address_space(1))) void*)g,
                                   (__attribute__((address_space(3))) void*)l,
                                   16, 0, 0);
}

__device__ __forceinline__ u32 pack_bf16(float a, float b) {
  u32 ua = (u32)__builtin_bit_cast(u16, (bf16_t)a);
  u32 ub = (u32)__builtin_bit_cast(u16, (bf16_t)b);
  return ua | (ub << 16);
}

// ---------------------------------------------------------------------------
// Kernel 1: scatter new k/v into caches -> f32 outputs; also bf16 K copy to ws.
// ---------------------------------------------------------------------------
__global__ __launch_bounds__(256) void update_cache_kernel(
    const float* __restrict__ knew,
    const float* __restrict__ vnew,
    const float* __restrict__ cache_k,
    const float* __restrict__ cache_v,
    const int*   __restrict__ seq_lens,
    float* __restrict__ new_ck,
    float* __restrict__ new_cv,
    bf16_t* __restrict__ kb)
{
  const int n4 = NB * NKVH * NL * ND / 4;
  for (int i = blockIdx.x * blockDim.x + threadIdx.x; i < 2 * n4;
       i += gridDim.x * blockDim.x) {
    const int which = i >= n4;
    const int j   = which ? i - n4 : i;
    const int d4  = j & 31;
    const int l   = (j >> 5) & (NL - 1);
    const int kvh = (j >> 16) & (NKVH - 1);
    const int b   = j >> 18;
    const int s   = seq_lens[b];
    float4 val;
    if (l >= s && l < s + NQL) {
      const float* nsrc = which ? vnew : knew;
      val = *(const float4*)(nsrc + (((size_t)(b * NQL + (l - s))) * NKVH + kvh) * ND + d4 * 4);
    } else {
      const float* csrc = which ? cache_v : cache_k;
      val = *(const float4*)(csrc + (((size_t)(b * NKVH + kvh)) * NL + l) * ND + d4 * 4);
    }
    const size_t coff = (((size_t)(b * NKVH + kvh)) * NL + l) * ND + d4 * 4;
    float* dst = which ? new_cv : new_ck;
    *(float4*)(dst + coff) = val;
    if (!which) {
      bf16x4 kv;
      kv[0] = (bf16_t)val.x; kv[1] = (bf16_t)val.y;
      kv[2] = (bf16_t)val.z; kv[3] = (bf16_t)val.w;
      *(bf16x4*)(kb + coff) = kv;
    }
  }
}

// ---------------------------------------------------------------------------
// Kernel 2: build bf16 V^T [B][KVH][D][L] from updated f32 V cache.
// ---------------------------------------------------------------------------
__global__ __launch_bounds__(256) void transpose_v_kernel(
    const float* __restrict__ new_cv, bf16_t* __restrict__ vt)
{
  __shared__ float T[64][129];
  const int tid = threadIdx.x;
  const int bid = blockIdx.x;        // B*KVH*(NL/64) = 512
  const int lt  = bid & 31;
  const int kvh = (bid >> 5) & (NKVH - 1);
  const int b   = bid >> 7;
  const int l0  = lt * 64;

  const float* src = new_cv + (((size_t)(b * NKVH + kvh)) * NL + l0) * ND;
  #pragma unroll
  for (int j = 0; j < 8; ++j) {
    const int i   = tid + j * 256;
    const int row = i >> 5, c4 = i & 31;
    float4 v = *(const float4*)(src + row * ND + c4 * 4);
    T[row][c4 * 4 + 0] = v.x; T[row][c4 * 4 + 1] = v.y;
    T[row][c4 * 4 + 2] = v.z; T[row][c4 * 4 + 3] = v.w;
  }
  __syncthreads();
  bf16_t* dst = vt + ((size_t)(b * NKVH + kvh)) * ND * NL;
  #pragma unroll
  for (int j = 0; j < 4; ++j) {
    const int c = tid + j * 256;
    const int d = c >> 3, l8 = c & 7;
    bf16x8 o;
    #pragma unroll
    for (int e = 0; e < 8; ++e) o[e] = (bf16_t)T[l8 * 8 + e][d];
    *(bf16x8*)(dst + (size_t)d * NL + l0 + l8 * 8) = o;
  }
}

// ---------------------------------------------------------------------------
// Kernel 3: KV-split pipelined flash attention, 32x32 swapped MFMA.
// Block = 4 waves x 32 q-rows; KVBLK=32; LDS 32 KB.
// launch_bounds(256,2): VGPR cap 256. (256,3)=168 and (256,4)=128 both SPILL
// the ~160-reg body (R7: FETCH 519MB @64 VGPR; R8: 103MB @84 VGPR) -- the
// spill tax exceeds any occupancy gain. HW still fits 3 blocks/CU via LDS.
// Schedule (verified R5): phase t: barrier; STAGE_K(cur, t+2);
// STAGE_V(cur^1, t+1); QKT(t+1 from Kl[cur^1]); SOFTPV(t from Vl[cur]).
// ---------------------------------------------------------------------------
// K tile: 32 rows x 256B (16 chunks), chunk ^= (row&7).
#define STAGE_K(buf, tt) do {                                                \
    const int l0s = (tt) * KVBLK;                                            \
    _Pragma("unroll")                                                        \
    for (int j = 0; j < 2; ++j) {                                            \
      const int ck = tid + j * 256;                                          \
      const int kr = ck >> 4, kc2 = (ck & 15) ^ (kr & 7);                    \
      gload_lds16(kbb + (size_t)(l0s + kr) * ND + kc2 * 8,                   \
                  &Kl[buf][(wave * 64 + j * 256) * 8]);                      \
    }                                                                        \
  } while (0)

// V^T tile: 128 rows x 64B (4 chunks), chunk ^= (row ^ (row>>2)) & 3.
#define STAGE_V(buf, tt) do {                                                \
    const int l0s = (tt) * KVBLK;                                            \
    _Pragma("unroll")                                                        \
    for (int j = 0; j < 2; ++j) {                                            \
      const int ck = tid + j * 256;                                          \
      const int vr = ck >> 2, vc2 = (ck & 3) ^ ((vr ^ (vr >> 2)) & 3);       \
      gload_lds16(vtb + (size_t)vr * NL + (l0s + vc2 * 8),                   \
                  &Vl[buf][(wave * 64 + j * 256) * 8]);                      \
    }                                                                        \
  } while (0)

// S^T(tile) = K.Q from Kl[KBI] into SB (f32x16); rows l = l5, cols q.
#define QKT(SB, KBI) do {                                                    \
    f32x16 acc = (f32x16)(0.f);                                              \
    _Pragma("unroll")                                                        \
    for (int kc = 0; kc < 8; ++kc) {                                         \
      bf16x8 kf = *(const bf16x8*)                                           \
          &Kl[KBI][(l5 * 16 + ((kc * 2 + hi5) ^ (l5 & 7))) * 8];             \
      acc = __builtin_amdgcn_mfma_f32_32x32x16_bf16(kf, qf[kc], acc, 0, 0, 0); \
    }                                                                        \
    SB = acc;                                                                \
  } while (0)

// mask + online softmax + PV for tile at L0 using SB and Vl[VBI].
// Lane holds S^T[l = (rr&3) + 8*(rr>>2) + 4*hi5][q = l5].
#define SOFTPV(SB, VBI, L0) do {                                             \
    if ((L0) + 31 > s + qw) {                                                \
      const int lim = s + q - (L0);                                          \
      _Pragma("unroll")                                                      \
      for (int rr = 0; rr < 16; ++rr) {                                      \
        const int ll = (rr & 3) + 8 * (rr >> 2) + 4 * hi5;                   \
        if (ll > lim) SB[rr] = -1e30f;                                       \
      }                                                                      \
    }                                                                        \
    float m0 = fmaxf(SB[0], SB[1]),   m1 = fmaxf(SB[2], SB[3]);              \
    float m2 = fmaxf(SB[4], SB[5]),   m3 = fmaxf(SB[6], SB[7]);              \
    float m4 = fmaxf(SB[8], SB[9]),   m5 = fmaxf(SB[10], SB[11]);            \
    float m6 = fmaxf(SB[12], SB[13]), m7 = fmaxf(SB[14], SB[15]);            \
    m0 = fmaxf(m0, m1); m2 = fmaxf(m2, m3);                                  \
    m4 = fmaxf(m4, m5); m6 = fmaxf(m6, m7);                                  \
    float pm = fmaxf(fmaxf(m0, m2), fmaxf(m4, m6));                          \
    pm = fmaxf(pm, __shfl_xor(pm, 32, 64));                                  \
    if (!__all(pm - mreg <= 8.f)) {                                          \
      const float mnew  = fmaxf(mreg, pm);                                   \
      const float alpha = exp2f(mreg - mnew);                                \
      mreg = mnew;                                                           \
      lreg *= alpha;                                                         \
      _Pragma("unroll")                                                      \
      for (int i = 0; i < 4; ++i) oacc[i] *= alpha;                          \
    }                                                                        \
    _Pragma("unroll")                                                        \
    for (int rr = 0; rr < 16; ++rr) SB[rr] = exp2f(SB[rr] - mreg);           \
    float s0 = (SB[0] + SB[1]) + (SB[2] + SB[3]);                            \
    float s1 = (SB[4] + SB[5]) + (SB[6] + SB[7]);                            \
    float s2 = (SB[8] + SB[9]) + (SB[10] + SB[11]);                          \
    float s3 = (SB[12] + SB[13]) + (SB[14] + SB[15]);                        \
    float ts = (s0 + s1) + (s2 + s3);                                        \
    lreg += ts + __shfl_xor(ts, 32, 64);                                     \
    u32 pk[4][2];                                                            \
    _Pragma("unroll")                                                        \
    for (int m = 0; m < 4; ++m) {                                            \
      pk[m][0] = pack_bf16(SB[m * 4 + 0], SB[m * 4 + 1]);                    \
      pk[m][1] = pack_bf16(SB[m * 4 + 2], SB[m * 4 + 3]);                    \
    }                                                                        \
    bf16x8 pb[2];                                                            \
    _Pragma("unroll")                                                        \
    for (int c = 0; c < 2; ++c) {                                            \
      const u32 own0 = hi5 ? pk[c * 2 + 1][0] : pk[c * 2][0];                \
      const u32 own1 = hi5 ? pk[c * 2 + 1][1] : pk[c * 2][1];                \
      const u32 snd0 = hi5 ? pk[c * 2][0] : pk[c * 2 + 1][0];                \
      const u32 snd1 = hi5 ? pk[c * 2][1] : pk[c * 2 + 1][1];                \
      const u32 r0 = (u32)__shfl_xor((int)snd0, 32, 64);                     \
      const u32 r1 = (u32)__shfl_xor((int)snd1, 32, 64);                     \
      union { u32 w[4]; bf16x8 v; } uu;                                      \
      uu.w[0] = hi5 ? r0 : own0;                                             \
      uu.w[1] = hi5 ? r1 : own1;                                             \
      uu.w[2] = hi5 ? own0 : r0;                                             \
      uu.w[3] = hi5 ? own1 : r1;                                             \
      pb[c] = uu.v;                                                          \
    }                                                                        \
    _Pragma("unroll")                                                        \
    for (int ds = 0; ds < 4; ++ds) {                                         \
      const int vrow = ds * 32 + l5;                                         \
      _Pragma("unroll")                                                      \
      for (int c = 0; c < 2; ++c) {                                          \
        bf16x8 va = *(const bf16x8*)                                         \
            &Vl[VBI][(vrow * 4 + ((c * 2 + hi5) ^ ((l5 ^ (l5 >> 2)) & 3))) * 8]; \
        oacc[ds] = __builtin_amdgcn_mfma_f32_32x32x16_bf16(va, pb[c], oacc[ds], 0, 0, 0); \
      }                                                                      \
    }                                                                        \
  } while (0)

__global__ __launch_bounds__(256, 2) void attn_kernel(
    const float* __restrict__ qin, const bf16_t* __restrict__ kb,
    const bf16_t* __restrict__ vt, const int* __restrict__ seq_lens,
    float* __restrict__ out, bf16_t* __restrict__ opart,
    float2* __restrict__ ml, int nspl)
{
  __shared__ bf16_t Kl[2][KVBLK * ND];   // 8 KB x2
  __shared__ bf16_t Vl[2][ND * KVBLK];   // 8 KB x2

  const int tid  = threadIdx.x;
  const int wave = tid >> 6, lane = tid & 63;
  const int l5   = lane & 31;            // q column / l-row index
  const int hi5  = lane >> 5;

  // LPT-ordered mapping: bid = chunk*256 + bk*16 + hh*4 + pp, idx = chunk*4+pp.
  // nspl==2: (qt,sp) = (7-(idx>>1), idx&1) -- expensive (big-qt) jobs dispatch
  // first, the 256 cheapest (qt 0-1) fill the tail. nspl==1: qt = 7-idx.
  // Co-resident chunks share (bk,hh) -> same K/V panel in L2.
  const int bid   = blockIdx.x;
  const int chunk = bid >> 8;
  const int r     = bid & 255;
  const int bk    = r >> 4;              // b*NKVH + kvh
  const int hh    = (r >> 2) & 3;
  const int pp    = r & 3;
  const int idx   = chunk * 4 + pp;
  const int qt    = (nspl == 2) ? (7 - (idx >> 1)) : (7 - idx);
  const int sp    = (nspl == 2) ? (idx & 1) : 0;
  const int kvh   = bk & (NKVH - 1);
  const int b     = bk >> 2;
  const int h     = kvh * 4 + hh;
  const int s     = seq_lens[b];
  const int qw    = qt * 128 + wave * 32;
  const int q     = qw + l5;

  const bf16_t* kbb = kb + ((size_t)bk) * NL * ND;
  const bf16_t* vtb = vt + ((size_t)bk) * ND * NL;

  // Q fragments (B operand): qf[kc][j] = Q[q][kc*16 + hi5*8 + j]
  bf16x8 qf[8];
  {
    const float* qb = qin + ((size_t)((b * NQL + q) * NH + h)) * ND;
    #pragma unroll
    for (int kc = 0; kc < 8; ++kc) {
      float4 x0 = *(const float4*)(qb + kc * 16 + hi5 * 8);
      float4 x1 = *(const float4*)(qb + kc * 16 + hi5 * 8 + 4);
      bf16x8 f;
      f[0] = (bf16_t)(x0.x * QSCALE_LOG2E); f[1] = (bf16_t)(x0.y * QSCALE_LOG2E);
      f[2] = (bf16_t)(x0.z * QSCALE_LOG2E); f[3] = (bf16_t)(x0.w * QSCALE_LOG2E);
      f[4] = (bf16_t)(x1.x * QSCALE_LOG2E); f[5] = (bf16_t)(x1.y * QSCALE_LOG2E);
      f[6] = (bf16_t)(x1.z * QSCALE_LOG2E); f[7] = (bf16_t)(x1.w * QSCALE_LOG2E);
      qf[kc] = f;
    }
  }

  f32x16 oacc[4];   // O^T[d = ds*32 + 8*rq + 4*hi5 + rr][q = l5]
  #pragma unroll
  for (int i = 0; i < 4; ++i) oacc[i] = (f32x16)(0.f);
  float mreg = -1e30f, lreg = 0.f;

  // block-level tile range for this KV split part (each part >= 2 tiles)
  const int nt   = (s + qt * 128 + 128 + KVBLK - 1) / KVBLK;   // >= 4
  const int half = (nspl == 2) ? ((nt + 1) >> 1) : nt;
  const int t0   = sp * half;
  const int t1   = (sp + 1 == nspl) ? nt : (t0 + half);
  const int vlim = s + qw + 31;          // wave's last valid l

  // ---- prologue: stage K(t0), V(t0), K(t0+1); compute QK(t0) ----
  STAGE_K(0, t0);
  STAGE_V(0, t0);
  STAGE_K(1, t0 + 1);
  __syncthreads();

  f32x16 sA, sB;
  QKT(sA, 0);

  // ---- main loop, 2 phases per trip, all buffer indices static ----
  for (int t = t0; ; t += 2) {
    // --- phase even: tile t uses Kl[0]/Vl[0] ---
    __syncthreads();                     // drains K(t+1)->Kl[1], V(t)->Vl[0]
    if (t + 2 < t1) STAGE_K(0, t + 2);
    if (t + 1 < t1) STAGE_V(1, t + 1);
    const bool gB = (t + 1 < t1) && ((t + 1) * KVBLK <= vlim);
    if (gB) QKT(sB, 1);
    if (t * KVBLK <= vlim) SOFTPV(sA, 0, t * KVBLK);
    if (t + 1 >= t1) break;

    // --- phase odd: tile t+1 uses Kl[1]/Vl[1] ---
    __syncthreads();                     // drains K(t+2)->Kl[0], V(t+1)->Vl[1]
    if (t + 3 < t1) STAGE_K(1, t + 3);
    if (t + 2 < t1) STAGE_V(0, t + 2);
    const bool gA = (t + 2 < t1) && ((t + 2) * KVBLK <= vlim);
    if (gA) QKT(sA, 0);
    if ((t + 1) * KVBLK <= vlim) SOFTPV(sB, 1, (t + 1) * KVBLK);
    if (t + 2 >= t1) break;
  }

  const int row = (b * NH + h) * NQL + q;
  if (nspl == 1) {
    // direct write (fallback): normalize, d = ds*32 + rq*8 + hi5*4 + rr
    const float linv = 1.0f / lreg;
    float* ob = out + ((size_t)((b * NQL + q) * NH + h)) * ND;
    #pragma unroll
    for (int ds = 0; ds < 4; ++ds)
      #pragma unroll
      for (int rq = 0; rq < 4; ++rq) {
        float4 v;
        v.x = oacc[ds][rq * 4 + 0] * linv;
        v.y = oacc[ds][rq * 4 + 1] * linv;
        v.z = oacc[ds][rq * 4 + 2] * linv;
        v.w = oacc[ds][rq * 4 + 3] * linv;
        *(float4*)(ob + ds * 32 + rq * 8 + hi5 * 4) = v;
      }
  } else {
    // partial write: unnormalized bf16 O + (m,l)
    bf16_t* ob = opart + ((size_t)sp * NROWS + row) * ND;
    #pragma unroll
    for (int ds = 0; ds < 4; ++ds)
      #pragma unroll
      for (int rq = 0; rq < 4; ++rq) {
        bf16x4 v;
        v[0] = (bf16_t)oacc[ds][rq * 4 + 0];
        v[1] = (bf16_t)oacc[ds][rq * 4 + 1];
        v[2] = (bf16_t)oacc[ds][rq * 4 + 2];
        v[3] = (bf16_t)oacc[ds][rq * 4 + 3];
        *(bf16x4*)(ob + ds * 32 + rq * 8 + hi5 * 4) = v;
      }
    if (hi5 == 0) ml[(size_t)sp * NROWS + row] = make_float2(mreg, lreg);
  }
}

// ---------------------------------------------------------------------------
// Kernel 4: merge the 2 KV-split partials. gid = row*32 + d4.
// ---------------------------------------------------------------------------
__global__ __launch_bounds__(256) void combine_kernel(
    const bf16_t* __restrict__ opart, const float2* __restrict__ ml,
    float* __restrict__ out)
{
  const int gid = blockIdx.x * 256 + threadIdx.x;   // NROWS*32 threads
  const int row = gid >> 5, d4 = gid & 31;
  const float2 ml0 = ml[row];
  const float2 ml1 = ml[NROWS + row];
  const float M  = fmaxf(ml0.x, ml1.x);
  const float a0 = exp2f(ml0.x - M), a1 = exp2f(ml1.x - M);
  const float linv = 1.0f / (a0 * ml0.y + a1 * ml1.y);
  bf16x4 o0 = *(const bf16x4*)(opart + (size_t)row * ND + d4 * 4);
  bf16x4 o1 = *(const bf16x4*)(opart + ((size_t)NROWS + row) * ND + d4 * 4);
  const int q = row & (NQL - 1), h = (row >> 10) & (NH - 1), b = row >> 14;
  float4 v;
  v.x = (a0 * (float)o0[0] + a1 * (float)o1[0]) * linv;
  v.y = (a0 * (float)o0[1] + a1 * (float)o1[1]) * linv;
  v.z = (a0 * (float)o0[2] + a1 * (float)o1[2]) * linv;
  v.w = (a0 * (float)o0[3] + a1 * (float)o1[3]) * linv;
  *(float4*)(out + ((size_t)((b * NQL + q) * NH + h)) * ND + d4 * 4) = v;
}

// ---------------------------------------------------------------------------
extern "C" void kernel_launch(void* const* d_in, const int* in_sizes, int n_in,
                              void* d_out, int out_size, void* d_ws, size_t ws_size,
                              hipStream_t stream)
{
  const float* q        = (const float*)d_in[0];
  const float* k        = (const float*)d_in[1];
  const float* v        = (const float*)d_in[2];
  const float* cache_k  = (const float*)d_in[3];
  const float* cache_v  = (const float*)d_in[4];
  const int*   seq_lens = (const int*)d_in[5];

  float* out    = (float*)d_out;
  float* new_ck = out + (size_t)NB * NQL * NH * ND;
  float* new_cv = new_ck + (size_t)NB * NKVH * NL * ND;

  const size_t cache_elems = (size_t)NB * NKVH * NL * ND;   // 4 Mi elems
  bf16_t* kb    = (bf16_t*)d_ws;                            // 8 MB
  bf16_t* vt    = kb + cache_elems;                         // 8 MB
  bf16_t* opart = vt + cache_elems;                         // 32 MB (2 parts)
  float2* ml    = (float2*)(opart + (size_t)2 * NROWS * ND);// 1 MB

  const size_t need = (size_t)((char*)(ml + 2 * NROWS) - (char*)d_ws);
  const int nspl = (ws_size >= need) ? 2 : 1;

  hipLaunchKernelGGL(update_cache_kernel, dim3(2048), dim3(256), 0, stream,
                     k, v, cache_k, cache_v, seq_lens, new_ck, new_cv, kb);
  hipLaunchKernelGGL(transpose_v_kernel, dim3(NB * NKVH * (NL / 64)), dim3(256), 0, stream,
                     new_cv, vt);
  hipLaunchKernelGGL(attn_kernel, dim3(nspl == 2 ? 1024 : 512), dim3(256), 0, stream,
                     q, kb, vt, seq_lens, out, opart, ml, nspl);
  if (nspl == 2)
    hipLaunchKernelGGL(combine_kernel, dim3(NROWS * 32 / 256), dim3(256), 0, stream,
                       opart, ml, out);
}